// Round 22
// baseline (31.067 us; speedup 1.0000x reference)
//
#include <hip/hip_runtime.h>
#include <math.h>

#define BATCH 128
#define NPWM 512
#define LEN 1000
#define KSLOT 80      // kk padded 19->20, slot = kk*4 + c; K chunks 32+32+16

typedef _Float16 f16x4 __attribute__((ext_vector_type(4)));
typedef _Float16 f16x8 __attribute__((ext_vector_type(8)));
typedef float    f32x4 __attribute__((ext_vector_type(4)));

#define MFMAK32(a, b, c) __builtin_amdgcn_mfma_f32_16x16x32_f16(a, b, c, 0, 0, 0)
#define MFMAK16(a, b, c) __builtin_amdgcn_mfma_f32_16x16x16f16(a, b, c, 0, 0, 0)

// 16B B-fragment as two naturally-8B-aligned ds_read_b64 (conflict-free, R14)
#define LDB(EO) __extension__ ({                                         \
    f16x4 p0_ = *(const f16x4*)(H + (EO));                               \
    f16x4 p1_ = *(const f16x4*)(H + (EO) + 4);                           \
    __builtin_shufflevector(p0_, p1_, 0,1,2,3,4,5,6,7); })

// ---- single-kernel: fused W-prepack (fp32->fp16 into LDS, per block) +
// single-term fp16 GEMM, mixed-shape K=80 (32+32+16), fg=4.
// block = 4 waves = 2 filter-halves(64 f_ext) x 2 position-halves.
// Per iter (2 pos-tiles = 32 pos): 10 x 8B LDS reads feed 20 MFMAs
// (4fg x 2tiles x {K32,K32,K16}) in 8 independent dep-3 chains.
// grid = (128,8) = 4 blocks/CU; LDS ~29.7KB -> 4 blocks/CU fits.
__global__ __launch_bounds__(256, 4)
void pwm_mfma(const float* __restrict__ x,
              const float* __restrict__ w,
              float* __restrict__ out)
{
    __shared__ __align__(16) _Float16 WT[128*KSLOT]; // block's W slice, [fe_local][slot]
    __shared__ __align__(16) _Float16 H[4096];       // fp16(x), [pos][c], tail 0
    __shared__ float red[2][128];

    const int tid   = threadIdx.x;
    const int b     = blockIdx.x;
    const int ftile = blockIdx.y;   // 0..7 (128 f_ext per block)
    const int lane  = tid & 63;
    const int wave  = tid >> 6;
    const int fhalf = wave & 1;     // which 64 f_ext
    const int wp    = wave >> 1;    // position half
    const int row   = lane & 15;    // position within 16-tile / W k-row
    const int g     = lane >> 4;    // k-group (0..3)

    // stage fp16(x[b]) position-major [pos][c]; 8B LDS writes, tail zeroed
    for (int i = tid; i < 1024; i += 256) {
        f16x4 hv;
        #pragma unroll
        for (int c = 0; c < 4; ++c) {
            float v = (i < LEN) ? x[(size_t)b*4000 + c*1000 + i] : 0.0f;
            hv[c] = (_Float16)v;
        }
        *(f16x4*)(H + i*4) = hv;
    }

    // fused W-prepack: fe = ftile*128 + j; f = fe>>1, strand = fe&1;
    // slot t: kk = t>>2, c = t&3; rev-comp for strand 1; zeros at kk >= 19.
    for (int i = tid; i < 128*KSLOT; i += 256) {
        const int j  = i / KSLOT;
        const int t  = i - j*KSLOT;
        const int kk = t >> 2;
        const int c  = t & 3;
        const int fe = ftile*128 + j;
        const int f  = fe >> 1;
        float v = 0.0f;
        if (kk < 19)
            v = (fe & 1) ? w[f*76 + (3-c)*19 + (18-kk)]
                         : w[f*76 + c*19 + kk];
        WT[i] = (_Float16)v;
    }
    __syncthreads();

    // A fragments from WT (LDS).
    // K32 chunks s=0,1: lane holds W[f][k = s*32 + g*8 + j] (f16x8).
    // K16 chunk: lane holds W[f][k = 64 + g*4 + j] (f16x4).
    f16x8 wa[4][2];
    f16x4 wa2[4];
    {
        const int f0l = fhalf*64;
        #pragma unroll
        for (int fg = 0; fg < 4; ++fg) {
            const int fo = (f0l + fg*16 + row)*KSLOT;
            #pragma unroll
            for (int s = 0; s < 2; ++s)
                wa[fg][s] = *(const f16x8*)(WT + fo + s*32 + g*8);
            wa2[fg] = *(const f16x4*)(WT + fo + 64 + g*4);
        }
    }
    __syncthreads();

    // B addressing (tile0 pos p = it*32 + row; tile1 = +16):
    //  K32 s: slot k = s*32+g*8+j -> x elem (p + s*8 + g*2)*4 ... 8 consecutive
    //  K16  : slot k = 64+g*4+j   -> x elem (p + 16 + g)*4   ... 4 consecutive
    const int base = row*4 + g*8;
    const f32x4 zc = {};

    float m[4][4];
    #pragma unroll
    for (int fg = 0; fg < 4; ++fg)
        #pragma unroll
        for (int r = 0; r < 4; ++r) m[fg][r] = -INFINITY;

    const int it_beg = wp ? 16 : 0;
    const int it_end = wp ? 31 : 16;
    for (int it = it_beg; it < it_end; ++it) {
        const int o_ = it*128 + base;
        f32x4 a0[4], a1[4];

        f16x8 g00 = LDB(o_);          // tile0 s0
        f16x8 g10 = LDB(o_ + 64);     // tile1 s0
        #pragma unroll
        for (int fg = 0; fg < 4; ++fg) a0[fg] = MFMAK32(wa[fg][0], g00, zc);
        #pragma unroll
        for (int fg = 0; fg < 4; ++fg) a1[fg] = MFMAK32(wa[fg][0], g10, zc);

        f16x8 g01 = LDB(o_ + 32);     // tile0 s1
        #pragma unroll
        for (int fg = 0; fg < 4; ++fg) a0[fg] = MFMAK32(wa[fg][1], g01, a0[fg]);
        f16x8 g11 = LDB(o_ + 96);     // tile1 s1
        #pragma unroll
        for (int fg = 0; fg < 4; ++fg) a1[fg] = MFMAK32(wa[fg][1], g11, a1[fg]);

        f16x4 b20 = *(const f16x4*)(H + it*128 + (row + 16 + g)*4);  // tile0 K16
        #pragma unroll
        for (int fg = 0; fg < 4; ++fg) a0[fg] = MFMAK16(wa2[fg], b20, a0[fg]);
        f16x4 b21 = *(const f16x4*)(H + it*128 + (row + 32 + g)*4);  // tile1 K16
        #pragma unroll
        for (int fg = 0; fg < 4; ++fg) a1[fg] = MFMAK16(wa2[fg], b21, a1[fg]);

        if (it == 30 && row >= 6) {   // tile1 pos = 976+row >= 982: exclude
            #pragma unroll
            for (int fg = 0; fg < 4; ++fg)
                #pragma unroll
                for (int r = 0; r < 4; ++r) a1[fg][r] = -INFINITY;
        }
        #pragma unroll
        for (int fg = 0; fg < 4; ++fg)
            #pragma unroll
            for (int r = 0; r < 4; ++r)
                m[fg][r] = fmaxf(m[fg][r], fmaxf(a0[fg][r], a1[fg][r]));
    }

    // reduce over the 16 position-columns (lane&15)
    #pragma unroll
    for (int off = 1; off < 16; off <<= 1)
        #pragma unroll
        for (int fg = 0; fg < 4; ++fg)
            #pragma unroll
            for (int r = 0; r < 4; ++r)
                m[fg][r] = fmaxf(m[fg][r], __shfl_xor(m[fg][r], off, 64));

    // D row (filter within 16-tile) = g*4 + r
    if (row == 0) {
        #pragma unroll
        for (int fg = 0; fg < 4; ++fg)
            #pragma unroll
            for (int r = 0; r < 4; ++r)
                red[wp][fhalf*64 + fg*16 + g*4 + r] = m[fg][r];
    }
    __syncthreads();
    if (tid < 64) {   // combine strand pairs (f_ext = 2f, 2f+1) and position halves
        float v0 = fmaxf(red[0][2*tid], red[0][2*tid+1]);
        float v1 = fmaxf(red[1][2*tid], red[1][2*tid+1]);
        out[(size_t)b*NPWM + ftile*64 + tid] = fmaxf(v0, v1);
    }
}

extern "C" void kernel_launch(void* const* d_in, const int* in_sizes, int n_in,
                              void* d_out, int out_size, void* d_ws, size_t ws_size,
                              hipStream_t stream)
{
    const float* x = (const float*)d_in[0];   // (128, 4, 1000)
    const float* w = (const float*)d_in[1];   // (512, 4, 19)
    float* out = (float*)d_out;               // (128, 512)

    pwm_mfma<<<dim3(BATCH, 8), 256, 0, stream>>>(x, w, out);
}

// Round 23
// 30.777 us; speedup vs baseline: 1.0094x; 1.0094x over previous
//
#include <hip/hip_runtime.h>
#include <math.h>

#define BATCH 128
#define NPWM 512
#define LEN 1000
#define NEXT 1024     // 2*NPWM (fwd + revcomp interleaved: f_ext = 2*f + strand)
#define KSLOT 80      // kk padded 19->20, slot = kk*4 + c; K chunks 32+32+16

typedef _Float16 f16x4 __attribute__((ext_vector_type(4)));
typedef _Float16 f16x8 __attribute__((ext_vector_type(8)));
typedef float    f32x4 __attribute__((ext_vector_type(4)));

#define MFMAK32(a, b, c) __builtin_amdgcn_mfma_f32_16x16x32_f16(a, b, c, 0, 0, 0)
#define MFMAK16(a, b, c) __builtin_amdgcn_mfma_f32_16x16x16f16(a, b, c, 0, 0, 0)

// ---- prepack W: (512,4,19) fp32 -> (1024,80) fp16, zeros at pad slots ----
// Single-term fp16: dot error ~ sqrt(76)*2^-11 ~ 0.02 abs (better than 2-term
// bf16 at half the MFMA count). RC strand = compile-time weight permutation.
__global__ __launch_bounds__(256)
void prepack_w(const float* __restrict__ w, _Float16* __restrict__ wf)
{
    int idx = blockIdx.x * 256 + threadIdx.x;
    if (idx >= NEXT * KSLOT) return;
    int fe = idx / KSLOT;
    int t  = idx - fe * KSLOT;
    int kk = t >> 2;
    int c  = t & 3;
    int f      = fe >> 1;
    int strand = fe & 1;
    float v = 0.0f;
    if (kk < 19)
        v = strand ? w[f*76 + (3-c)*19 + (18-kk)]   // reverse-complement
                   : w[f*76 + c*19 + kk];
    wf[idx] = (_Float16)v;
}

// 16B B-fragment as two naturally-8B-aligned ds_read_b64 (conflict-free, R14)
#define LDB(EO) __extension__ ({                                         \
    f16x4 p0_ = *(const f16x4*)(H + (EO));                               \
    f16x4 p1_ = *(const f16x4*)(H + (EO) + 4);                           \
    __builtin_shufflevector(p0_, p1_, 0,1,2,3,4,5,6,7); })

// ---- main: single-term fp16 GEMM, mixed-shape K=80 (32+32+16), fg=4.
// block = 4 waves = 2 filter-halves(64 f_ext) x 2 position-halves.
// Per iter (2 pos-tiles = 32 pos): 10 x 8B LDS reads feed 20 MFMAs
// (4fg x 2tiles x {K32,K32,K16}) in 8 independent dep-3 chains.
// K padding 4/80 slots. grid = (128,8) = 4 blocks/CU; VGPR ~115 -> 4 waves/SIMD.
// Session best: 30.7 us (~36% of fp16 MFMA peak; serial-phase structural cap).
__global__ __launch_bounds__(256, 4)
void pwm_mfma(const float* __restrict__ x,
              const _Float16* __restrict__ wf,
              float* __restrict__ out)
{
    __shared__ __align__(16) _Float16 H[4096];   // fp16(x), [pos][c], tail 0
    __shared__ float red[2][128];

    const int tid   = threadIdx.x;
    const int b     = blockIdx.x;
    const int ftile = blockIdx.y;   // 0..7 (128 f_ext per block)
    const int lane  = tid & 63;
    const int wave  = tid >> 6;
    const int fhalf = wave & 1;     // which 64 f_ext
    const int wp    = wave >> 1;    // position half
    const int row   = lane & 15;    // position within 16-tile / W k-row
    const int g     = lane >> 4;    // k-group (0..3)

    // stage fp16(x[b]) position-major [pos][c]; 8B LDS writes, tail zeroed
    for (int i = tid; i < 1024; i += 256) {
        f16x4 hv;
        #pragma unroll
        for (int c = 0; c < 4; ++c) {
            float v = (i < LEN) ? x[(size_t)b*4000 + c*1000 + i] : 0.0f;
            hv[c] = (_Float16)v;
        }
        *(f16x4*)(H + i*4) = hv;
    }

    // A fragments -> regs.
    // K32 chunks s=0,1: lane holds W[f][k = s*32 + g*8 + j], j=0..7 (f16x8).
    // K16 chunk: lane holds W[f][k = 64 + g*4 + j], j=0..3 (f16x4).
    f16x8 wa[4][2];
    f16x4 wa2[4];
    {
        const int f0 = ftile*128 + fhalf*64;
        #pragma unroll
        for (int fg = 0; fg < 4; ++fg) {
            const size_t fo = (size_t)(f0 + fg*16 + row)*KSLOT;
            #pragma unroll
            for (int s = 0; s < 2; ++s)
                wa[fg][s] = *(const f16x8*)(wf + fo + s*32 + g*8);
            wa2[fg] = *(const f16x4*)(wf + fo + 64 + g*4);
        }
    }
    __syncthreads();

    // B addressing (tile0 pos p = it*32 + row; tile1 = +16):
    //  K32 s: slot k = s*32+g*8+j -> x elem (p + s*8 + g*2)*4 ... 8 consecutive
    //  K16  : slot k = 64+g*4+j   -> x elem (p + 16 + g)*4   ... 4 consecutive
    const int base = row*4 + g*8;
    const f32x4 zc = {};

    float m[4][4];
    #pragma unroll
    for (int fg = 0; fg < 4; ++fg)
        #pragma unroll
        for (int r = 0; r < 4; ++r) m[fg][r] = -INFINITY;

    const int it_beg = wp ? 16 : 0;
    const int it_end = wp ? 31 : 16;
    for (int it = it_beg; it < it_end; ++it) {
        const int o_ = it*128 + base;
        f32x4 a0[4], a1[4];

        f16x8 g00 = LDB(o_);          // tile0 s0
        f16x8 g10 = LDB(o_ + 64);     // tile1 s0
        #pragma unroll
        for (int fg = 0; fg < 4; ++fg) a0[fg] = MFMAK32(wa[fg][0], g00, zc);
        #pragma unroll
        for (int fg = 0; fg < 4; ++fg) a1[fg] = MFMAK32(wa[fg][0], g10, zc);

        f16x8 g01 = LDB(o_ + 32);     // tile0 s1
        #pragma unroll
        for (int fg = 0; fg < 4; ++fg) a0[fg] = MFMAK32(wa[fg][1], g01, a0[fg]);
        f16x8 g11 = LDB(o_ + 96);     // tile1 s1
        #pragma unroll
        for (int fg = 0; fg < 4; ++fg) a1[fg] = MFMAK32(wa[fg][1], g11, a1[fg]);

        f16x4 b20 = *(const f16x4*)(H + it*128 + (row + 16 + g)*4);  // tile0 K16
        #pragma unroll
        for (int fg = 0; fg < 4; ++fg) a0[fg] = MFMAK16(wa2[fg], b20, a0[fg]);
        f16x4 b21 = *(const f16x4*)(H + it*128 + (row + 32 + g)*4);  // tile1 K16
        #pragma unroll
        for (int fg = 0; fg < 4; ++fg) a1[fg] = MFMAK16(wa2[fg], b21, a1[fg]);

        if (it == 30 && row >= 6) {   // tile1 pos = 976+row >= 982: exclude
            #pragma unroll
            for (int fg = 0; fg < 4; ++fg)
                #pragma unroll
                for (int r = 0; r < 4; ++r) a1[fg][r] = -INFINITY;
        }
        #pragma unroll
        for (int fg = 0; fg < 4; ++fg)
            #pragma unroll
            for (int r = 0; r < 4; ++r)
                m[fg][r] = fmaxf(m[fg][r], fmaxf(a0[fg][r], a1[fg][r]));
    }

    // reduce over the 16 position-columns (lane&15)
    #pragma unroll
    for (int off = 1; off < 16; off <<= 1)
        #pragma unroll
        for (int fg = 0; fg < 4; ++fg)
            #pragma unroll
            for (int r = 0; r < 4; ++r)
                m[fg][r] = fmaxf(m[fg][r], __shfl_xor(m[fg][r], off, 64));

    // D row (filter within 16-tile) = g*4 + r
    if (row == 0) {
        #pragma unroll
        for (int fg = 0; fg < 4; ++fg)
            #pragma unroll
            for (int r = 0; r < 4; ++r)
                red[wp][fhalf*64 + fg*16 + g*4 + r] = m[fg][r];
    }
    __syncthreads();
    if (tid < 64) {   // combine strand pairs (f_ext = 2f, 2f+1) and position halves
        float v0 = fmaxf(red[0][2*tid], red[0][2*tid+1]);
        float v1 = fmaxf(red[1][2*tid], red[1][2*tid+1]);
        out[(size_t)b*NPWM + ftile*64 + tid] = fmaxf(v0, v1);
    }
}

extern "C" void kernel_launch(void* const* d_in, const int* in_sizes, int n_in,
                              void* d_out, int out_size, void* d_ws, size_t ws_size,
                              hipStream_t stream)
{
    const float* x = (const float*)d_in[0];   // (128, 4, 1000)
    const float* w = (const float*)d_in[1];   // (512, 4, 19)
    float* out = (float*)d_out;               // (128, 512)

    _Float16* wf = (_Float16*)d_ws;           // 1024*80 fp16

    prepack_w<<<dim3((NEXT*KSLOT + 255)/256), 256, 0, stream>>>(w, wf);
    pwm_mfma<<<dim3(BATCH, 8), 256, 0, stream>>>(x, wf, out);
}